// Round 7
// baseline (961.018 us; speedup 1.0000x reference)
//
#include <hip/hip_runtime.h>
#include <hip/hip_bf16.h>

// ---------------- problem constants ----------------
constexpr int B_   = 8;
constexpr int D_   = 512;
constexpr int L0_  = 1024;
constexpr int L_   = 1025;          // L0 + cls
constexpr int H_   = 8;
constexpr int DH_  = 64;
constexpr int DFF_ = 2048;
constexpr int NLAYER_ = 2;
constexpr int M_   = B_ * L_;       // 8200 rows
constexpr int LP_  = 1088;          // padded L for Vt (17*64)
constexpr float EPS_   = 1e-6f;
constexpr float SCALE_ = 0.125f;    // 1/sqrt(64)

#define DEV_INLINE __device__ __forceinline__

typedef __attribute__((ext_vector_type(8))) __bf16 bf16x8;
typedef __attribute__((ext_vector_type(4))) __bf16 bf16x4;
typedef __attribute__((ext_vector_type(4))) float  f32x4;
typedef __attribute__((ext_vector_type(4))) unsigned int u32x4;

union U4 { uint32_t u[4]; bf16x8 f; };

DEV_INLINE float gelu_exact(float x) {
    return 0.5f * x * (1.f + erff(x * 0.70710678118654752f));
}

struct bfpair { __bf16 h, l; };
DEV_INLINE bfpair split_bf(float v) {
    bfpair p;
    p.h = (__bf16)v;
    p.l = (__bf16)(v - (float)p.h);
    return p;
}
DEV_INLINE uint16_t bfbits(float v) {
    __bf16 h = (__bf16)v;
    return __builtin_bit_cast(uint16_t, h);
}
DEV_INLINE uint32_t pk2f(float a, float b) {
    return (uint32_t)bfbits(a) | ((uint32_t)bfbits(b) << 16);
}
DEV_INLINE float bflo(float v) { return v - (float)((__bf16)v); }

// ---------------- weight pre-split: fp32 -> bf16 hi/lo ----------------
__global__ __launch_bounds__(256) void split_w_kernel(
    const float* __restrict__ src, __bf16* __restrict__ hi,
    __bf16* __restrict__ lo, int n4) {
    int i = blockIdx.x * 256 + threadIdx.x;
    if (i >= n4) return;
    float4 v = *(const float4*)&src[i * 4];
    bf16x4 h, l;
    bfpair p0 = split_bf(v.x); h[0] = p0.h; l[0] = p0.l;
    bfpair p1 = split_bf(v.y); h[1] = p1.h; l[1] = p1.l;
    bfpair p2 = split_bf(v.z); h[2] = p2.h; l[2] = p2.l;
    bfpair p3 = split_bf(v.w); h[3] = p3.h; l[3] = p3.l;
    *(bf16x4*)&hi[i * 4] = h;
    *(bf16x4*)&lo[i * 4] = l;
}

// ---------------- build x1/x2 ----------------
__global__ __launch_bounds__(256) void write_cls_kernel(
    const float* __restrict__ cls, float* __restrict__ X1, float* __restrict__ X2) {
    int idx = blockIdx.x * 256 + threadIdx.x;
    int b = idx >> 9;
    int d = idx & 511;
    float v = cls[d];
    X1[(size_t)b * L_ * D_ + d] = v;
    X2[(size_t)b * L_ * D_ + d] = v;
}

// embed [B, D, L0] -> X rows 1..L0
__global__ __launch_bounds__(256) void transpose_embed_kernel(
    const float* __restrict__ e, float* __restrict__ X) {
    __shared__ float tile[32][33];
    int b  = blockIdx.z;
    int i0 = blockIdx.x * 32;
    int d0 = blockIdx.y * 32;
    int tx = threadIdx.x;
    int ty = threadIdx.y;
#pragma unroll
    for (int j = 0; j < 32; j += 8)
        tile[ty + j][tx] = e[((size_t)b * D_ + d0 + ty + j) * L0_ + i0 + tx];
    __syncthreads();
#pragma unroll
    for (int j = 0; j < 32; j += 8)
        X[((size_t)b * L_ + 1 + i0 + ty + j) * D_ + d0 + tx] = tile[tx][ty + j];
}

// V hi/lo bf16 [M,D] -> Vt hi/lo [B*H, DH, LP_] (zero-padded beyond L)
__global__ __launch_bounds__(256) void transpose_v_kernel(
    const __bf16* __restrict__ Vhg, const __bf16* __restrict__ Vlg,
    __bf16* __restrict__ Vth, __bf16* __restrict__ Vtl) {
    __shared__ __bf16 th[32][34];
    __shared__ __bf16 tl[32][34];
    int bh = blockIdx.z;
    int l0 = blockIdx.x * 32;
    int d0 = blockIdx.y * 32;
    int b = bh >> 3, h = bh & 7;
    int tx = threadIdx.x, ty = threadIdx.y;
#pragma unroll
    for (int j = 0; j < 32; j += 8) {
        int l = l0 + ty + j;
        __bf16 vh = (__bf16)0.f, vl = (__bf16)0.f;
        if (l < L_) {
            size_t o = ((size_t)(b * L_ + l)) * D_ + h * DH_ + d0 + tx;
            vh = Vhg[o]; vl = Vlg[o];
        }
        th[ty + j][tx] = vh;
        tl[ty + j][tx] = vl;
    }
    __syncthreads();
#pragma unroll
    for (int j = 0; j < 32; j += 8) {
        size_t o = ((size_t)bh * DH_ + d0 + ty + j) * LP_ + l0 + tx;
        Vth[o] = th[tx][ty + j];
        Vtl[o] = tl[tx][ty + j];
    }
}

// ---------------- split-bf16 MFMA GEMM (pre-split W, fp32 A) ----------------
// C = A * W^T + bias; W given as bf16 hi/lo. Output: fp32 (opt GELU) or bf16 hi/lo.
template <bool GELU, bool SPLITOUT>
__global__ __launch_bounds__(256) void gemm_mfma_kernel(
    const float* __restrict__ A,
    const __bf16* __restrict__ Wh, const __bf16* __restrict__ Wl,
    const float* __restrict__ bias, float* __restrict__ C,
    __bf16* __restrict__ Ch, __bf16* __restrict__ Cl,
    int M, int N, int K) {
    constexpr int BM = 128, BN = 64, BK = 32;
    constexpr int LDK = BK + 8;
    __shared__ alignas(16) __bf16 Ahs[BM][LDK];
    __shared__ alignas(16) __bf16 Als[BM][LDK];
    __shared__ alignas(16) __bf16 Bhs[BN][LDK];
    __shared__ alignas(16) __bf16 Bls[BN][LDK];

    const int GM = (M + BM - 1) / BM;
    const int nwg = gridDim.x;
    int bid = blockIdx.x;
    {
        int q = nwg >> 3, r = nwg & 7;
        int xcd = bid & 7, pos = bid >> 3;
        bid = (xcd < r) ? xcd * (q + 1) + pos
                        : r * (q + 1) + (xcd - r) * q + pos;
    }
    const int bn = bid / GM;
    const int bm = bid % GM;
    const int m0 = bm * BM;
    const int n0 = bn * BN;

    const int tid  = threadIdx.x;
    const int lane = tid & 63;
    const int wv   = tid >> 6;
    const int wr   = wv >> 1;
    const int wc   = wv & 1;
    const int fr   = lane & 15;
    const int fq   = lane >> 4;
    const int fq8  = fq * 8;
    const int mb   = wr * 64;
    const int nb   = wc * 32;

    // A staging: fp32, split on the fly
    const int srow = tid >> 3;
    const int sq   = tid & 7;
    size_t aOff[4];
#pragma unroll
    for (int rep = 0; rep < 4; ++rep) {
        int r = m0 + srow + rep * 32;
        if (r > M - 1) r = M - 1;
        aOff[rep] = (size_t)r * K + sq * 4;
    }
    // W staging: pre-split bf16, 16B copies
    const int swr = tid >> 2;      // 0..63
    const int swq = tid & 3;       // x8 elems
    const size_t wOff = (size_t)(n0 + swr) * K + swq * 8;

    f32x4 acc[4][2];
#pragma unroll
    for (int i = 0; i < 4; ++i)
#pragma unroll
        for (int j = 0; j < 2; ++j) acc[i][j] = (f32x4){0.f, 0.f, 0.f, 0.f};

    const int nk = K / BK;
    float4 aR[4];
    u32x4 wRh, wRl;
#pragma unroll
    for (int rep = 0; rep < 4; ++rep) aR[rep] = *(const float4*)&A[aOff[rep]];
    wRh = *(const u32x4*)&Wh[wOff];
    wRl = *(const u32x4*)&Wl[wOff];

    for (int kt = 0; kt < nk; ++kt) {
#pragma unroll
        for (int rep = 0; rep < 4; ++rep) {
            int row = srow + rep * 32;
            bf16x4 h, l;
            bfpair p0 = split_bf(aR[rep].x); h[0] = p0.h; l[0] = p0.l;
            bfpair p1 = split_bf(aR[rep].y); h[1] = p1.h; l[1] = p1.l;
            bfpair p2 = split_bf(aR[rep].z); h[2] = p2.h; l[2] = p2.l;
            bfpair p3 = split_bf(aR[rep].w); h[3] = p3.h; l[3] = p3.l;
            *(bf16x4*)&Ahs[row][sq * 4] = h;
            *(bf16x4*)&Als[row][sq * 4] = l;
        }
        *(u32x4*)&Bhs[swr][swq * 8] = wRh;
        *(u32x4*)&Bls[swr][swq * 8] = wRl;
        __syncthreads();

        if (kt + 1 < nk) {
            int k0 = (kt + 1) * BK;
#pragma unroll
            for (int rep = 0; rep < 4; ++rep) aR[rep] = *(const float4*)&A[aOff[rep] + k0];
            wRh = *(const u32x4*)&Wh[wOff + k0];
            wRl = *(const u32x4*)&Wl[wOff + k0];
        }

        bf16x8 ah[4], al[4], bh[2], bl[2];
#pragma unroll
        for (int i = 0; i < 4; ++i) {
            ah[i] = *(bf16x8*)&Ahs[mb + i * 16 + fr][fq8];
            al[i] = *(bf16x8*)&Als[mb + i * 16 + fr][fq8];
        }
#pragma unroll
        for (int j = 0; j < 2; ++j) {
            bh[j] = *(bf16x8*)&Bhs[nb + j * 16 + fr][fq8];
            bl[j] = *(bf16x8*)&Bls[nb + j * 16 + fr][fq8];
        }
#pragma unroll
        for (int i = 0; i < 4; ++i)
#pragma unroll
            for (int j = 0; j < 2; ++j)
                acc[i][j] = __builtin_amdgcn_mfma_f32_16x16x32_bf16(ah[i], bh[j], acc[i][j], 0, 0, 0);
#pragma unroll
        for (int i = 0; i < 4; ++i)
#pragma unroll
            for (int j = 0; j < 2; ++j)
                acc[i][j] = __builtin_amdgcn_mfma_f32_16x16x32_bf16(ah[i], bl[j], acc[i][j], 0, 0, 0);
#pragma unroll
        for (int i = 0; i < 4; ++i)
#pragma unroll
            for (int j = 0; j < 2; ++j)
                acc[i][j] = __builtin_amdgcn_mfma_f32_16x16x32_bf16(al[i], bh[j], acc[i][j], 0, 0, 0);
        __syncthreads();
    }

    const int ccol0 = n0 + nb + fr;
    const float b0 = bias[ccol0];
    const float b1 = bias[ccol0 + 16];
#pragma unroll
    for (int i = 0; i < 4; ++i) {
#pragma unroll
        for (int r = 0; r < 4; ++r) {
            int row = m0 + mb + i * 16 + fq * 4 + r;
            if (row < M) {
                float v0 = acc[i][0][r] + b0;
                float v1 = acc[i][1][r] + b1;
                if (GELU) { v0 = gelu_exact(v0); v1 = gelu_exact(v1); }
                if (SPLITOUT) {
                    bfpair s0 = split_bf(v0), s1 = split_bf(v1);
                    Ch[(size_t)row * N + ccol0]      = s0.h;
                    Cl[(size_t)row * N + ccol0]      = s0.l;
                    Ch[(size_t)row * N + ccol0 + 16] = s1.h;
                    Cl[(size_t)row * N + ccol0 + 16] = s1.l;
                } else {
                    C[(size_t)row * N + ccol0]      = v0;
                    C[(size_t)row * N + ccol0 + 16] = v1;
                }
            }
        }
    }
}

// ---------------- MFMA flash attention v3 (8 waves, pre-split bf16 QKV) ----------------
// grid (9, H, B), block 512 = 8 waves. Wave wv owns q rows q0+16wv..+15 (QT=128).
// S^T = mfma(K, Q): lane holds P^T[k][q=fr] -> lane-local softmax.
// PV a-frags assembled in-register via packed-quad shuffles. V pre-transposed (bf16 hi/lo).
__global__ __launch_bounds__(512) void attn_mfma_kernel(
    const __bf16* __restrict__ Qhg, const __bf16* __restrict__ Qlg,
    const __bf16* __restrict__ Khg, const __bf16* __restrict__ Klg,
    const __bf16* __restrict__ Vthg, const __bf16* __restrict__ Vtlg,
    float* __restrict__ O) {
    constexpr int LDP = 72;     // 144B row stride -> conflict-free b128 frag reads
    __shared__ alignas(16) __bf16 Kh[64][LDP], Klo[64][LDP];
    __shared__ alignas(16) __bf16 Vh[64][LDP], Vlo[64][LDP];

    const int tid  = threadIdx.x;
    const int lane = tid & 63;
    const int wv   = tid >> 6;          // 0..7
    const int fr   = lane & 15;
    const int fq   = lane >> 4;
    const int fq8  = fq * 8;
    const int qt = blockIdx.x, h = blockIdx.y, b = blockIdx.z;
    const int q0 = qt * 128;
    const int bh = b * H_ + h;
    const size_t base = (size_t)b * L_ * D_ + h * DH_;

    // ---- Q fragments direct from pre-split global ----
    bf16x8 bqh[2], bql[2];
    {
        int gq = q0 + 16 * wv + fr; if (gq > L_ - 1) gq = L_ - 1;
        const size_t qoff = (size_t)(b * L_ + gq) * D_ + h * DH_;
#pragma unroll
        for (int s = 0; s < 2; ++s) {
            bqh[s] = *(const bf16x8*)&Qhg[qoff + s * 32 + fq8];
            bql[s] = *(const bf16x8*)&Qlg[qoff + s * 32 + fq8];
        }
    }

    float m = -1e30f, l = 0.f;
    f32x4 oA[4];
#pragma unroll
    for (int c = 0; c < 4; ++c) oA[c] = (f32x4){0.f, 0.f, 0.f, 0.f};

    const int sr = tid >> 3;          // 0..63
    const int sc = tid & 7;           // x8 elems (16B)

    for (int kt = 0; kt < L_; kt += 64) {
        __syncthreads();
        // ---- stage K rows + Vt rows: pure 16B copies ----
        {
            int gr = kt + sr; if (gr > L_ - 1) gr = L_ - 1;
            const size_t kOff = (size_t)(b * L_ + gr) * D_ + h * DH_ + sc * 8;
            *(u32x4*)&Kh[sr][sc * 8]  = *(const u32x4*)&Khg[kOff];
            *(u32x4*)&Klo[sr][sc * 8] = *(const u32x4*)&Klg[kOff];
            const size_t vOff = ((size_t)bh * DH_ + sr) * LP_ + kt + sc * 8;
            *(u32x4*)&Vh[sr][sc * 8]  = *(const u32x4*)&Vthg[vOff];
            *(u32x4*)&Vlo[sr][sc * 8] = *(const u32x4*)&Vtlg[vOff];
        }
        __syncthreads();

        // ---- S^T slice: rows k = 16c+4fq+rr, col q = fr ----
        float p[4][4];
#pragma unroll
        for (int c = 0; c < 4; ++c) {
            int row = 16 * c + fr;
            bf16x8 ah0 = *(bf16x8*)&Kh[row][fq8];
            bf16x8 ah1 = *(bf16x8*)&Kh[row][32 + fq8];
            bf16x8 al0 = *(bf16x8*)&Klo[row][fq8];
            bf16x8 al1 = *(bf16x8*)&Klo[row][32 + fq8];
            f32x4 s = (f32x4){0.f, 0.f, 0.f, 0.f};
            s = __builtin_amdgcn_mfma_f32_16x16x32_bf16(ah0, bqh[0], s, 0, 0, 0);
            s = __builtin_amdgcn_mfma_f32_16x16x32_bf16(ah1, bqh[1], s, 0, 0, 0);
            s = __builtin_amdgcn_mfma_f32_16x16x32_bf16(ah0, bql[0], s, 0, 0, 0);
            s = __builtin_amdgcn_mfma_f32_16x16x32_bf16(ah1, bql[1], s, 0, 0, 0);
            s = __builtin_amdgcn_mfma_f32_16x16x32_bf16(al0, bqh[0], s, 0, 0, 0);
            s = __builtin_amdgcn_mfma_f32_16x16x32_bf16(al1, bqh[1], s, 0, 0, 0);
#pragma unroll
            for (int rr = 0; rr < 4; ++rr) {
                int k = kt + 16 * c + 4 * fq + rr;
                p[c][rr] = (k < L_) ? s[rr] * SCALE_ : -1e30f;
            }
        }

        // ---- lane-local online softmax for q = fr ----
        float t = p[0][0];
#pragma unroll
        for (int c = 0; c < 4; ++c)
#pragma unroll
            for (int rr = 0; rr < 4; ++rr) t = fmaxf(t, p[c][rr]);
        t = fmaxf(t, __shfl_xor(t, 16));
        t = fmaxf(t, __shfl_xor(t, 32));
        float mn = fmaxf(m, t);
        float sclq = __expf(m - mn);
        m = mn;
        float ls = 0.f;
#pragma unroll
        for (int c = 0; c < 4; ++c)
#pragma unroll
            for (int rr = 0; rr < 4; ++rr) {
                float e = __expf(p[c][rr] - m);
                p[c][rr] = e;
                ls += e;
            }
        ls += __shfl_xor(ls, 16);
        ls += __shfl_xor(ls, 32);
        l = l * sclq + ls;

#pragma unroll
        for (int rr = 0; rr < 4; ++rr) {
            float sO = __shfl(sclq, 4 * fq + rr);
#pragma unroll
            for (int c2 = 0; c2 < 4; ++c2) oA[c2][rr] *= sO;
        }

        // ---- pack P^T quads, hi/lo ----
        uint32_t pqh[4][2], pql[4][2];
#pragma unroll
        for (int c = 0; c < 4; ++c) {
            pqh[c][0] = pk2f(p[c][0], p[c][1]);
            pqh[c][1] = pk2f(p[c][2], p[c][3]);
            pql[c][0] = pk2f(bflo(p[c][0]), bflo(p[c][1]));
            pql[c][1] = pk2f(bflo(p[c][2]), bflo(p[c][3]));
        }

        // ---- assemble PV a-frags via shuffles ----
        const int src0 = fr + ((fq & 1) << 5);
        const int src1 = src0 + 16;
        const bool sel = (fq >> 1) != 0;
        bf16x8 pah[2], pal[2];
#pragma unroll
        for (int s = 0; s < 2; ++s) {
            const int c0 = 2 * s, c1 = 2 * s + 1;
            uint32_t A0 = (uint32_t)__shfl((int)pqh[c0][0], src0);
            uint32_t A1 = (uint32_t)__shfl((int)pqh[c0][1], src0);
            uint32_t A2 = (uint32_t)__shfl((int)pqh[c0][0], src1);
            uint32_t A3 = (uint32_t)__shfl((int)pqh[c0][1], src1);
            uint32_t B0 = (uint32_t)__shfl((int)pqh[c1][0], src0);
            uint32_t B1 = (uint32_t)__shfl((int)pqh[c1][1], src0);
            uint32_t B2 = (uint32_t)__shfl((int)pqh[c1][0], src1);
            uint32_t B3 = (uint32_t)__shfl((int)pqh[c1][1], src1);
            U4 uh;
            uh.u[0] = sel ? B0 : A0; uh.u[1] = sel ? B1 : A1;
            uh.u[2] = sel ? B2 : A2; uh.u[3] = sel ? B3 : A3;
            pah[s] = uh.f;
            uint32_t C0 = (uint32_t)__shfl((int)pql[c0][0], src0);
            uint32_t C1 = (uint32_t)__shfl((int)pql[c0][1], src0);
            uint32_t C2 = (uint32_t)__shfl((int)pql[c0][0], src1);
            uint32_t C3 = (uint32_t)__shfl((int)pql[c0][1], src1);
            uint32_t D0 = (uint32_t)__shfl((int)pql[c1][0], src0);
            uint32_t D1 = (uint32_t)__shfl((int)pql[c1][1], src0);
            uint32_t D2 = (uint32_t)__shfl((int)pql[c1][0], src1);
            uint32_t D3 = (uint32_t)__shfl((int)pql[c1][1], src1);
            U4 ul;
            ul.u[0] = sel ? D0 : C0; ul.u[1] = sel ? D1 : C1;
            ul.u[2] = sel ? D2 : C2; ul.u[3] = sel ? D3 : C3;
            pal[s] = ul.f;
        }

        // ---- O += P · V ----
#pragma unroll
        for (int c2 = 0; c2 < 4; ++c2) {
            int row = 16 * c2 + fr;
            bf16x8 bh0 = *(bf16x8*)&Vh[row][fq8];
            bf16x8 bh1 = *(bf16x8*)&Vh[row][32 + fq8];
            bf16x8 bl0 = *(bf16x8*)&Vlo[row][fq8];
            bf16x8 bl1 = *(bf16x8*)&Vlo[row][32 + fq8];
            f32x4 o = oA[c2];
            o = __builtin_amdgcn_mfma_f32_16x16x32_bf16(pah[0], bh0, o, 0, 0, 0);
            o = __builtin_amdgcn_mfma_f32_16x16x32_bf16(pah[1], bh1, o, 0, 0, 0);
            o = __builtin_amdgcn_mfma_f32_16x16x32_bf16(pah[0], bl0, o, 0, 0, 0);
            o = __builtin_amdgcn_mfma_f32_16x16x32_bf16(pah[1], bl1, o, 0, 0, 0);
            o = __builtin_amdgcn_mfma_f32_16x16x32_bf16(pal[0], bh0, o, 0, 0, 0);
            o = __builtin_amdgcn_mfma_f32_16x16x32_bf16(pal[1], bh1, o, 0, 0, 0);
            oA[c2] = o;
        }
    }

    // ---- epilogue ----
#pragma unroll
    for (int rr = 0; rr < 4; ++rr) {
        float lO = __shfl(l, 4 * fq + rr);
        int row = q0 + 16 * wv + 4 * fq + rr;
        if (row < L_) {
            float inv = 1.f / lO;
#pragma unroll
            for (int c2 = 0; c2 < 4; ++c2)
                O[base + (size_t)row * D_ + 16 * c2 + fr] = oA[c2][rr] * inv;
        }
    }
}

// ---------------- fused residual add + LayerNorm ----------------
__global__ __launch_bounds__(256) void add_ln_kernel(
    const float* __restrict__ X, const float* __restrict__ Y,
    const float* __restrict__ g, const float* __restrict__ be,
    float* __restrict__ Out) {
    int wave = threadIdx.x >> 6;
    int lane = threadIdx.x & 63;
    int row = blockIdx.x * 4 + wave;
    if (row >= M_) return;
    size_t base = (size_t)row * D_;
    int c0 = lane * 4, c1 = 256 + lane * 4;
    float4 xa = *(const float4*)&X[base + c0];
    float4 xb = *(const float4*)&X[base + c1];
    float4 ya = *(const float4*)&Y[base + c0];
    float4 yb = *(const float4*)&Y[base + c1];
    float v[8] = {xa.x + ya.x, xa.y + ya.y, xa.z + ya.z, xa.w + ya.w,
                  xb.x + yb.x, xb.y + yb.y, xb.z + yb.z, xb.w + yb.w};
    float s = 0.f, s2 = 0.f;
#pragma unroll
    for (int i = 0; i < 8; ++i) { s += v[i]; s2 = fmaf(v[i], v[i], s2); }
#pragma unroll
    for (int off = 32; off > 0; off >>= 1) {
        s  += __shfl_xor(s, off);
        s2 += __shfl_xor(s2, off);
    }
    float mean = s * (1.f / D_);
    float var  = s2 * (1.f / D_) - mean * mean;
    float rstd = rsqrtf(var + EPS_);
    float4 ga = *(const float4*)&g[c0];
    float4 gb = *(const float4*)&g[c1];
    float4 ba = *(const float4*)&be[c0];
    float4 bb = *(const float4*)&be[c1];
    float4 oa, ob;
    oa.x = (v[0] - mean) * rstd * ga.x + ba.x;
    oa.y = (v[1] - mean) * rstd * ga.y + ba.y;
    oa.z = (v[2] - mean) * rstd * ga.z + ba.z;
    oa.w = (v[3] - mean) * rstd * ga.w + ba.w;
    ob.x = (v[4] - mean) * rstd * gb.x + bb.x;
    ob.y = (v[5] - mean) * rstd * gb.y + bb.y;
    ob.z = (v[6] - mean) * rstd * gb.z + bb.z;
    ob.w = (v[7] - mean) * rstd * gb.w + bb.w;
    *(float4*)&Out[base + c0] = oa;
    *(float4*)&Out[base + c1] = ob;
}

// ---------------- launch ----------------
extern "C" void kernel_launch(void* const* d_in, const int* in_sizes, int n_in,
                              void* d_out, int out_size, void* d_ws, size_t ws_size,
                              hipStream_t stream) {
    const float* embed1 = (const float*)d_in[0];
    const float* embed2 = (const float*)d_in[1];
    const float* cls    = (const float*)d_in[2];
    const float* Wq = (const float*)d_in[3];
    const float* bq = (const float*)d_in[4];
    const float* Wk = (const float*)d_in[5];
    const float* bk = (const float*)d_in[6];
    const float* Wv = (const float*)d_in[7];
    const float* bv = (const float*)d_in[8];
    const float* Wo = (const float*)d_in[9];
    const float* bo = (const float*)d_in[10];
    const float* ln1g = (const float*)d_in[11];
    const float* ln1b = (const float*)d_in[12];
    const float* W1 = (const float*)d_in[13];
    const float* b1 = (const float*)d_in[14];
    const float* W2 = (const float*)d_in[15];
    const float* b2 = (const float*)d_in[16];
    const float* ln2g = (const float*)d_in[17];
    const float* ln2b = (const float*)d_in[18];

    const size_t SZ = (size_t)M_ * D_;        // 4,198,400 floats
    float* ws = (float*)d_ws;
    float* X  = ws;                            // [0, SZ)
    float* X2 = ws + SZ;                       // [SZ, 2SZ)
    float* Tb = ws + 2 * SZ;                   // [2SZ, 3SZ) attn out / FFN2 out
    __bf16* Qhb = (__bf16*)(ws + 3 * SZ);      // [3SZ,4SZ): Qh | Ql
    __bf16* Qlb = Qhb + SZ;
    __bf16* Khb = (__bf16*)(ws + 4 * SZ);
    __bf16* Klb = Khb + SZ;
    __bf16* Vhb = (__bf16*)(ws + 5 * SZ);
    __bf16* Vlb = Vhb + SZ;
    float* Hb = ws + 6 * SZ;                   // [6SZ,10SZ) fp32 [M,DFF] (FFN phase)
    __bf16* Vth = (__bf16*)(ws + 6 * SZ);      // aliases Hb (attn phase)
    __bf16* Vtl = Vth + (size_t)B_ * H_ * DH_ * LP_;
    float* WoOut = ws + 8 * SZ;                // [8SZ,9SZ) (attn phase tail)
    __bf16* wreg = (__bf16*)(ws + 10 * SZ);    // weights hi/lo region

    // weight region layout (bf16 elems)
    const size_t NQ = (size_t)NLAYER_ * D_ * D_;       // 524288
    const size_t NF = (size_t)NLAYER_ * DFF_ * D_;     // 2097152
    __bf16* Wqh = wreg;            __bf16* Wql = Wqh + NQ;
    __bf16* Wkh = Wql + NQ;        __bf16* Wkl = Wkh + NQ;
    __bf16* Wvh = Wkl + NQ;        __bf16* Wvl = Wvh + NQ;
    __bf16* Woh = Wvl + NQ;        __bf16* Wol = Woh + NQ;
    __bf16* W1h = Wol + NQ;        __bf16* W1l = W1h + NF;
    __bf16* W2h = W1l + NF;        __bf16* W2l = W2h + NF;

    // pre-split weights (once per call; deterministic)
    split_w_kernel<<<(int)(NQ / 4 + 255) / 256, 256, 0, stream>>>(Wq, Wqh, Wql, (int)(NQ / 4));
    split_w_kernel<<<(int)(NQ / 4 + 255) / 256, 256, 0, stream>>>(Wk, Wkh, Wkl, (int)(NQ / 4));
    split_w_kernel<<<(int)(NQ / 4 + 255) / 256, 256, 0, stream>>>(Wv, Wvh, Wvl, (int)(NQ / 4));
    split_w_kernel<<<(int)(NQ / 4 + 255) / 256, 256, 0, stream>>>(Wo, Woh, Wol, (int)(NQ / 4));
    split_w_kernel<<<(int)(NF / 4 + 255) / 256, 256, 0, stream>>>(W1, W1h, W1l, (int)(NF / 4));
    split_w_kernel<<<(int)(NF / 4 + 255) / 256, 256, 0, stream>>>(W2, W2h, W2l, (int)(NF / 4));

    write_cls_kernel<<<(B_ * D_) / 256, 256, 0, stream>>>(cls, X, X2);
    transpose_embed_kernel<<<dim3(L0_ / 32, D_ / 32, B_), dim3(32, 8), 0, stream>>>(embed1, X);
    transpose_embed_kernel<<<dim3(L0_ / 32, D_ / 32, B_), dim3(32, 8), 0, stream>>>(embed2, X2);

    const int GM = (M_ + 127) / 128;         // 65
    const int g512  = GM * (512 / 64);       // 520
    const int g2048 = GM * (2048 / 64);      // 2080

    for (int l = 0; l < NLAYER_; ++l) {
        const size_t oQ = (size_t)l * D_ * D_;
        const size_t oF = (size_t)l * DFF_ * D_;

        gemm_mfma_kernel<false, true><<<g512, 256, 0, stream>>>(
            X, Wqh + oQ, Wql + oQ, bq + l * D_, nullptr, Qhb, Qlb, M_, D_, D_);
        gemm_mfma_kernel<false, true><<<g512, 256, 0, stream>>>(
            X2, Wkh + oQ, Wkl + oQ, bk + l * D_, nullptr, Khb, Klb, M_, D_, D_);
        gemm_mfma_kernel<false, true><<<g512, 256, 0, stream>>>(
            X2, Wvh + oQ, Wvl + oQ, bv + l * D_, nullptr, Vhb, Vlb, M_, D_, D_);

        transpose_v_kernel<<<dim3(LP_ / 32, DH_ / 32, B_ * H_), dim3(32, 8), 0, stream>>>(
            Vhb, Vlb, Vth, Vtl);

        attn_mfma_kernel<<<dim3((L_ + 127) / 128, H_, B_), 512, 0, stream>>>(
            Qhb, Qlb, Khb, Klb, Vth, Vtl, Tb);

        gemm_mfma_kernel<false, false><<<g512, 256, 0, stream>>>(
            Tb, Woh + oQ, Wol + oQ, bo + l * D_, WoOut, nullptr, nullptr, M_, D_, D_);

        add_ln_kernel<<<(M_ + 3) / 4, 256, 0, stream>>>(
            X, WoOut, ln1g + l * D_, ln1b + l * D_, X);

        gemm_mfma_kernel<true, false><<<g2048, 256, 0, stream>>>(
            X, W1h + oF, W1l + oF, b1 + l * DFF_, Hb, nullptr, nullptr, M_, DFF_, D_);
        gemm_mfma_kernel<false, false><<<g512, 256, 0, stream>>>(
            Hb, W2h + oF, W2l + oF, b2 + l * D_, Tb, nullptr, nullptr, M_, D_, DFF_);

        float* out_ptr = (l == NLAYER_ - 1) ? (float*)d_out : X;
        add_ln_kernel<<<(M_ + 3) / 4, 256, 0, stream>>>(
            X, Tb, ln2g + l * D_, ln2b + l * D_, out_ptr);
    }
}

// Round 8
// 953.880 us; speedup vs baseline: 1.0075x; 1.0075x over previous
//
#include <hip/hip_runtime.h>
#include <hip/hip_bf16.h>

// ---------------- problem constants ----------------
constexpr int B_   = 8;
constexpr int D_   = 512;
constexpr int L0_  = 1024;
constexpr int L_   = 1025;          // L0 + cls
constexpr int H_   = 8;
constexpr int DH_  = 64;
constexpr int DFF_ = 2048;
constexpr int NLAYER_ = 2;
constexpr int M_   = B_ * L_;       // 8200 rows
constexpr int LP_  = 1088;          // padded L for Vt (17*64)
constexpr float EPS_   = 1e-6f;
constexpr float SCALE_ = 0.125f;    // 1/sqrt(64)

#define DEV_INLINE __device__ __forceinline__

typedef __attribute__((ext_vector_type(8))) __bf16 bf16x8;
typedef __attribute__((ext_vector_type(4))) __bf16 bf16x4;
typedef __attribute__((ext_vector_type(4))) float  f32x4;
typedef __attribute__((ext_vector_type(4))) unsigned int u32x4;

union U4 { uint32_t u[4]; bf16x8 f; };

DEV_INLINE float gelu_exact(float x) {
    return 0.5f * x * (1.f + erff(x * 0.70710678118654752f));
}

struct bfpair { __bf16 h, l; };
DEV_INLINE bfpair split_bf(float v) {
    bfpair p;
    p.h = (__bf16)v;
    p.l = (__bf16)(v - (float)p.h);
    return p;
}
DEV_INLINE uint16_t bfbits(float v) {
    __bf16 h = (__bf16)v;
    return __builtin_bit_cast(uint16_t, h);
}
DEV_INLINE uint32_t pk2f(float a, float b) {
    return (uint32_t)bfbits(a) | ((uint32_t)bfbits(b) << 16);
}
DEV_INLINE float bflo(float v) { return v - (float)((__bf16)v); }
// packed element: hi in low 16, lo in high 16
DEV_INLINE uint32_t pkhl(float v) {
    bfpair s = split_bf(v);
    return (uint32_t)__builtin_bit_cast(uint16_t, s.h)
         | ((uint32_t)__builtin_bit_cast(uint16_t, s.l) << 16);
}
// 8 packed u32 -> hi bf16x8 + lo bf16x8
DEV_INLINE void unpk8(const uint32_t* r, bf16x8& h, bf16x8& l) {
    U4 uh, ul;
#pragma unroll
    for (int i = 0; i < 4; ++i) {
        uint32_t a = r[2 * i], b = r[2 * i + 1];
        uh.u[i] = (a & 0xffffu) | (b << 16);
        ul.u[i] = (a >> 16) | (b & 0xffff0000u);
    }
    h = uh.f; l = ul.f;
}

// ---------------- weight pre-split: fp32 -> bf16 hi/lo planes ----------------
__global__ __launch_bounds__(256) void split_w_kernel(
    const float* __restrict__ src, __bf16* __restrict__ hi,
    __bf16* __restrict__ lo, int n4) {
    int i = blockIdx.x * 256 + threadIdx.x;
    if (i >= n4) return;
    float4 v = *(const float4*)&src[i * 4];
    bf16x4 h, l;
    bfpair p0 = split_bf(v.x); h[0] = p0.h; l[0] = p0.l;
    bfpair p1 = split_bf(v.y); h[1] = p1.h; l[1] = p1.l;
    bfpair p2 = split_bf(v.z); h[2] = p2.h; l[2] = p2.l;
    bfpair p3 = split_bf(v.w); h[3] = p3.h; l[3] = p3.l;
    *(bf16x4*)&hi[i * 4] = h;
    *(bf16x4*)&lo[i * 4] = l;
}

// ---------------- build x1/x2 ----------------
__global__ __launch_bounds__(256) void write_cls_kernel(
    const float* __restrict__ cls, float* __restrict__ X1, float* __restrict__ X2) {
    int idx = blockIdx.x * 256 + threadIdx.x;
    int b = idx >> 9;
    int d = idx & 511;
    float v = cls[d];
    X1[(size_t)b * L_ * D_ + d] = v;
    X2[(size_t)b * L_ * D_ + d] = v;
}

// embed [B, D, L0] -> X rows 1..L0
__global__ __launch_bounds__(256) void transpose_embed_kernel(
    const float* __restrict__ e, float* __restrict__ X) {
    __shared__ float tile[32][33];
    int b  = blockIdx.z;
    int i0 = blockIdx.x * 32;
    int d0 = blockIdx.y * 32;
    int tx = threadIdx.x;
    int ty = threadIdx.y;
#pragma unroll
    for (int j = 0; j < 32; j += 8)
        tile[ty + j][tx] = e[((size_t)b * D_ + d0 + ty + j) * L0_ + i0 + tx];
    __syncthreads();
#pragma unroll
    for (int j = 0; j < 32; j += 8)
        X[((size_t)b * L_ + 1 + i0 + ty + j) * D_ + d0 + tx] = tile[tx][ty + j];
}

// V packed [M,D] u32 -> Vt packed [B*H, DH, LP_] u32 (zero beyond L)
__global__ __launch_bounds__(256) void transpose_v_kernel(
    const uint32_t* __restrict__ V, uint32_t* __restrict__ Vt) {
    __shared__ uint32_t tile[32][33];
    int bh = blockIdx.z;
    int l0 = blockIdx.x * 32;
    int d0 = blockIdx.y * 32;
    int b = bh >> 3, h = bh & 7;
    int tx = threadIdx.x, ty = threadIdx.y;
#pragma unroll
    for (int j = 0; j < 32; j += 8) {
        int l = l0 + ty + j;
        uint32_t v = 0u;
        if (l < L_) v = V[((size_t)(b * L_ + l)) * D_ + h * DH_ + d0 + tx];
        tile[ty + j][tx] = v;
    }
    __syncthreads();
#pragma unroll
    for (int j = 0; j < 32; j += 8)
        Vt[((size_t)bh * DH_ + d0 + ty + j) * LP_ + l0 + tx] = tile[tx][ty + j];
}

// ---------------- split-bf16 MFMA GEMM (pre-split W planes, fp32 A) ----------------
// C = A*W^T + bias. OUT: PK=false -> fp32 C; PK=true -> packed u32 (hi|lo).
template <bool GELU, bool PK>
__global__ __launch_bounds__(256) void gemm_mfma_kernel(
    const float* __restrict__ A,
    const __bf16* __restrict__ Wh, const __bf16* __restrict__ Wl,
    const float* __restrict__ bias, float* __restrict__ C,
    uint32_t* __restrict__ Cpk, int M, int N, int K) {
    constexpr int BM = 128, BN = 64, BK = 32;
    constexpr int LDK = BK + 8;
    __shared__ alignas(16) __bf16 Ahs[BM][LDK];
    __shared__ alignas(16) __bf16 Als[BM][LDK];
    __shared__ alignas(16) __bf16 Bhs[BN][LDK];
    __shared__ alignas(16) __bf16 Bls[BN][LDK];

    const int GM = (M + BM - 1) / BM;
    const int nwg = gridDim.x;
    int bid = blockIdx.x;
    {
        int q = nwg >> 3, r = nwg & 7;
        int xcd = bid & 7, pos = bid >> 3;
        bid = (xcd < r) ? xcd * (q + 1) + pos
                        : r * (q + 1) + (xcd - r) * q + pos;
    }
    const int bn = bid / GM;
    const int bm = bid % GM;
    const int m0 = bm * BM;
    const int n0 = bn * BN;

    const int tid  = threadIdx.x;
    const int lane = tid & 63;
    const int wv   = tid >> 6;
    const int wr   = wv >> 1;
    const int wc   = wv & 1;
    const int fr   = lane & 15;
    const int fq   = lane >> 4;
    const int fq8  = fq * 8;
    const int mb   = wr * 64;
    const int nb   = wc * 32;

    const int srow = tid >> 3;
    const int sq   = tid & 7;
    size_t aOff[4];
#pragma unroll
    for (int rep = 0; rep < 4; ++rep) {
        int r = m0 + srow + rep * 32;
        if (r > M - 1) r = M - 1;
        aOff[rep] = (size_t)r * K + sq * 4;
    }
    const int swr = tid >> 2;
    const int swq = tid & 3;
    const size_t wOff = (size_t)(n0 + swr) * K + swq * 8;

    f32x4 acc[4][2];
#pragma unroll
    for (int i = 0; i < 4; ++i)
#pragma unroll
        for (int j = 0; j < 2; ++j) acc[i][j] = (f32x4){0.f, 0.f, 0.f, 0.f};

    const int nk = K / BK;
    float4 aR[4];
    u32x4 wRh, wRl;
#pragma unroll
    for (int rep = 0; rep < 4; ++rep) aR[rep] = *(const float4*)&A[aOff[rep]];
    wRh = *(const u32x4*)&Wh[wOff];
    wRl = *(const u32x4*)&Wl[wOff];

    for (int kt = 0; kt < nk; ++kt) {
#pragma unroll
        for (int rep = 0; rep < 4; ++rep) {
            int row = srow + rep * 32;
            bf16x4 h, l;
            bfpair p0 = split_bf(aR[rep].x); h[0] = p0.h; l[0] = p0.l;
            bfpair p1 = split_bf(aR[rep].y); h[1] = p1.h; l[1] = p1.l;
            bfpair p2 = split_bf(aR[rep].z); h[2] = p2.h; l[2] = p2.l;
            bfpair p3 = split_bf(aR[rep].w); h[3] = p3.h; l[3] = p3.l;
            *(bf16x4*)&Ahs[row][sq * 4] = h;
            *(bf16x4*)&Als[row][sq * 4] = l;
        }
        *(u32x4*)&Bhs[swr][swq * 8] = wRh;
        *(u32x4*)&Bls[swr][swq * 8] = wRl;
        __syncthreads();

        if (kt + 1 < nk) {
            int k0 = (kt + 1) * BK;
#pragma unroll
            for (int rep = 0; rep < 4; ++rep) aR[rep] = *(const float4*)&A[aOff[rep] + k0];
            wRh = *(const u32x4*)&Wh[wOff + k0];
            wRl = *(const u32x4*)&Wl[wOff + k0];
        }

        bf16x8 ah[4], al[4], bh[2], bl[2];
#pragma unroll
        for (int i = 0; i < 4; ++i) {
            ah[i] = *(bf16x8*)&Ahs[mb + i * 16 + fr][fq8];
            al[i] = *(bf16x8*)&Als[mb + i * 16 + fr][fq8];
        }
#pragma unroll
        for (int j = 0; j < 2; ++j) {
            bh[j] = *(bf16x8*)&Bhs[nb + j * 16 + fr][fq8];
            bl[j] = *(bf16x8*)&Bls[nb + j * 16 + fr][fq8];
        }
#pragma unroll
        for (int i = 0; i < 4; ++i)
#pragma unroll
            for (int j = 0; j < 2; ++j)
                acc[i][j] = __builtin_amdgcn_mfma_f32_16x16x32_bf16(ah[i], bh[j], acc[i][j], 0, 0, 0);
#pragma unroll
        for (int i = 0; i < 4; ++i)
#pragma unroll
            for (int j = 0; j < 2; ++j)
                acc[i][j] = __builtin_amdgcn_mfma_f32_16x16x32_bf16(ah[i], bl[j], acc[i][j], 0, 0, 0);
#pragma unroll
        for (int i = 0; i < 4; ++i)
#pragma unroll
            for (int j = 0; j < 2; ++j)
                acc[i][j] = __builtin_amdgcn_mfma_f32_16x16x32_bf16(al[i], bh[j], acc[i][j], 0, 0, 0);
        __syncthreads();
    }

    const int ccol0 = n0 + nb + fr;
    const float b0 = bias[ccol0];
    const float b1 = bias[ccol0 + 16];
#pragma unroll
    for (int i = 0; i < 4; ++i) {
#pragma unroll
        for (int r = 0; r < 4; ++r) {
            int row = m0 + mb + i * 16 + fq * 4 + r;
            if (row < M) {
                float v0 = acc[i][0][r] + b0;
                float v1 = acc[i][1][r] + b1;
                if (GELU) { v0 = gelu_exact(v0); v1 = gelu_exact(v1); }
                if (PK) {
                    Cpk[(size_t)row * N + ccol0]      = pkhl(v0);
                    Cpk[(size_t)row * N + ccol0 + 16] = pkhl(v1);
                } else {
                    C[(size_t)row * N + ccol0]      = v0;
                    C[(size_t)row * N + ccol0 + 16] = v1;
                }
            }
        }
    }
}

// ---------------- MFMA flash attention v4 ----------------
// block 256 = 4 waves, each wave owns 32 q rows (2 groups of 16). QT=128.
// K/V staged as packed u32 (hi|lo), async reg prefetch. Frag reads shared
// across both q-groups -> LDS traffic per MFMA halved vs v3.
__global__ __launch_bounds__(256) void attn_mfma_kernel(
    const uint32_t* __restrict__ Qpk, const uint32_t* __restrict__ Kpk,
    const uint32_t* __restrict__ Vtpk, float* __restrict__ O) {
    constexpr int LDU = 68;     // u32 row stride (272B)
    __shared__ alignas(16) uint32_t Kls[64][LDU];
    __shared__ alignas(16) uint32_t Vls[64][LDU];

    const int tid  = threadIdx.x;
    const int lane = tid & 63;
    const int wv   = tid >> 6;          // 0..3
    const int fr   = lane & 15;
    const int fq   = lane >> 4;
    const int fq8  = fq * 8;
    const int qt = blockIdx.x, h = blockIdx.y, b = blockIdx.z;
    const int q0 = qt * 128 + wv * 32;  // this wave's 32 q rows
    const int bh = b * H_ + h;
    const size_t obase = (size_t)b * L_ * D_ + h * DH_;

    // ---- Q fragments (B-operand), 2 groups, unpacked from packed global ----
    bf16x8 bqh[2][2], bql[2][2];
#pragma unroll
    for (int g = 0; g < 2; ++g) {
        int gq = q0 + 16 * g + fr; if (gq > L_ - 1) gq = L_ - 1;
        const uint32_t* qrow = Qpk + (size_t)(b * L_ + gq) * D_ + h * DH_;
#pragma unroll
        for (int s = 0; s < 2; ++s) {
            uint32_t r[8];
            *(u32x4*)&r[0] = *(const u32x4*)&qrow[s * 32 + fq8];
            *(u32x4*)&r[4] = *(const u32x4*)&qrow[s * 32 + fq8 + 4];
            unpk8(r, bqh[g][s], bql[g][s]);
        }
    }

    float m[2] = {-1e30f, -1e30f};
    float lsum[2] = {0.f, 0.f};
    f32x4 oA[2][4];
#pragma unroll
    for (int g = 0; g < 2; ++g)
#pragma unroll
        for (int c = 0; c < 4; ++c) oA[g][c] = (f32x4){0.f, 0.f, 0.f, 0.f};

    // staging geometry: 256 threads, 64B (16 u32) per thread per array
    const int sr = tid >> 2;            // 0..63
    const int sc = (tid & 3) * 16;      // col start (u32)
    const size_t kRowBase = (size_t)(b * L_) * D_ + h * DH_ + sc;
    const size_t vRowBase = ((size_t)bh * DH_ + sr) * LP_ + sc;

    u32x4 kR[4], vR[4];
    // prologue: load + write tile 0
    {
        int gr = sr; if (gr > L_ - 1) gr = L_ - 1;
        const uint32_t* kp = Kpk + kRowBase + (size_t)gr * D_;
        const uint32_t* vp = Vtpk + vRowBase;
#pragma unroll
        for (int i = 0; i < 4; ++i) { kR[i] = *(const u32x4*)&kp[i * 4]; vR[i] = *(const u32x4*)&vp[i * 4]; }
#pragma unroll
        for (int i = 0; i < 4; ++i) {
            *(u32x4*)&Kls[sr][sc + i * 4] = kR[i];
            *(u32x4*)&Vls[sr][sc + i * 4] = vR[i];
        }
    }

    constexpr int NT = (L_ + 63) / 64;   // 17
    for (int t = 0; t < NT; ++t) {
        const int kt = t * 64;
        __syncthreads();                 // staged tile visible

        // ---- issue next tile's global loads (hide under compute) ----
        if (t + 1 < NT) {
            int gr = kt + 64 + sr; if (gr > L_ - 1) gr = L_ - 1;
            const uint32_t* kp = Kpk + kRowBase + (size_t)gr * D_;
            const uint32_t* vp = Vtpk + vRowBase + (kt + 64);
#pragma unroll
            for (int i = 0; i < 4; ++i) { kR[i] = *(const u32x4*)&kp[i * 4]; vR[i] = *(const u32x4*)&vp[i * 4]; }
        }

        // ---- S^T slices, both groups (K frags shared) ----
        float p0[4][4], p1[4][4];
#pragma unroll
        for (int c = 0; c < 4; ++c) {
            const int row = 16 * c + fr;
            uint32_t r[8];
            bf16x8 ah0, al0, ah1, al1;
            *(u32x4*)&r[0] = *(u32x4*)&Kls[row][fq8];
            *(u32x4*)&r[4] = *(u32x4*)&Kls[row][fq8 + 4];
            unpk8(r, ah0, al0);
            *(u32x4*)&r[0] = *(u32x4*)&Kls[row][32 + fq8];
            *(u32x4*)&r[4] = *(u32x4*)&Kls[row][32 + fq8 + 4];
            unpk8(r, ah1, al1);
#pragma unroll
            for (int g = 0; g < 2; ++g) {
                f32x4 s = (f32x4){0.f, 0.f, 0.f, 0.f};
                s = __builtin_amdgcn_mfma_f32_16x16x32_bf16(ah0, bqh[g][0], s, 0, 0, 0);
                s = __builtin_amdgcn_mfma_f32_16x16x32_bf16(ah1, bqh[g][1], s, 0, 0, 0);
                s = __builtin_amdgcn_mfma_f32_16x16x32_bf16(ah0, bql[g][0], s, 0, 0, 0);
                s = __builtin_amdgcn_mfma_f32_16x16x32_bf16(ah1, bql[g][1], s, 0, 0, 0);
                s = __builtin_amdgcn_mfma_f32_16x16x32_bf16(al0, bqh[g][0], s, 0, 0, 0);
                s = __builtin_amdgcn_mfma_f32_16x16x32_bf16(al1, bqh[g][1], s, 0, 0, 0);
#pragma unroll
                for (int rr = 0; rr < 4; ++rr) {
                    int k = kt + 16 * c + 4 * fq + rr;
                    float val = (k < L_) ? s[rr] * SCALE_ : -1e30f;
                    if (g == 0) p0[c][rr] = val; else p1[c][rr] = val;
                }
            }
        }

        // ---- per-group lane-local online softmax + pack + shuffle + PV frags ----
        bf16x8 pah[2][2], pal[2][2];
#pragma unroll
        for (int g = 0; g < 2; ++g) {
            float (*p)[4] = (g == 0) ? p0 : p1;
            float t0 = p[0][0];
#pragma unroll
            for (int c = 0; c < 4; ++c)
#pragma unroll
                for (int rr = 0; rr < 4; ++rr) t0 = fmaxf(t0, p[c][rr]);
            t0 = fmaxf(t0, __shfl_xor(t0, 16));
            t0 = fmaxf(t0, __shfl_xor(t0, 32));
            float mn = fmaxf(m[g], t0);
            float sclq = __expf(m[g] - mn);
            m[g] = mn;
            float ls = 0.f;
#pragma unroll
            for (int c = 0; c < 4; ++c)
#pragma unroll
                for (int rr = 0; rr < 4; ++rr) {
                    float e = __expf(p[c][rr] - mn);
                    p[c][rr] = e;
                    ls += e;
                }
            ls += __shfl_xor(ls, 16);
            ls += __shfl_xor(ls, 32);
            lsum[g] = lsum[g] * sclq + ls;
#pragma unroll
            for (int rr = 0; rr < 4; ++rr) {
                float sO = __shfl(sclq, 4 * fq + rr);
#pragma unroll
                for (int c2 = 0; c2 < 4; ++c2) oA[g][c2][rr] *= sO;
            }

            uint32_t pqh[4][2], pql[4][2];
#pragma unroll
            for (int c = 0; c < 4; ++c) {
                pqh[c][0] = pk2f(p[c][0], p[c][1]);
                pqh[c][1] = pk2f(p[c][2], p[c][3]);
                pql[c][0] = pk2f(bflo(p[c][0]), bflo(p[c][1]));
                pql[c][1] = pk2f(bflo(p[c][2]), bflo(p[c][3]));
            }
            const int src0 = fr + ((fq & 1) << 5);
            const int src1 = src0 + 16;
            const bool sel = (fq >> 1) != 0;
#pragma unroll
            for (int s = 0; s < 2; ++s) {
                const int c0 = 2 * s, c1 = 2 * s + 1;
                uint32_t A0 = (uint32_t)__shfl((int)pqh[c0][0], src0);
                uint32_t A1 = (uint32_t)__shfl((int)pqh[c0][1], src0);
                uint32_t A2 = (uint32_t)__shfl((int)pqh[c0][0], src1);
                uint32_t A3 = (uint32_t)__shfl((int)pqh[c0][1], src1);
                uint32_t B0 = (uint32_t)__shfl((int)pqh[c1][0], src0);
                uint32_t B1 = (uint32_t)__shfl((int)pqh[c1][1], src0);
                uint32_t B2 = (uint32_t)__shfl((int)pqh[c1][0], src1);
                uint32_t B3 = (uint32_t)__shfl((int)pqh[c1][1], src1);
                U4 uh;
                uh.u[0] = sel ? B0 : A0; uh.u[1] = sel ? B1 : A1;
                uh.u[2] = sel ? B2 : A2; uh.u[3] = sel ? B3 : A3;
                pah[g][s] = uh.f;
                uint32_t C0 = (uint32_t)__shfl((int)pql[c0][0], src0);
                uint32_t C1 = (uint32_t)__shfl((int)pql[c0][1], src0);
                uint32_t C2 = (uint32_t)__shfl((int)pql[c0][0], src1);
                uint32_t C3 = (uint32_t)__shfl((int)pql[c0][1], src1);
                uint32_t D0 = (uint32_t)__shfl((int)pql[c1][0], src0);
                uint32_t D1 = (uint32_t)__shfl((int)pql[c1][1], src0);
                uint32_t D2 = (uint32_t)__shfl((int)pql[c1][0], src1);
                uint32_t D3 = (uint32_t)__shfl((int)pql[c1][1], src1);
                U4 ul;
                ul.u[0] = sel ? D0 : C0; ul.u[1] = sel ? D1 : C1;
                ul.u[2] = sel ? D2 : C2; ul.u[3] = sel ? D3 : C3;
                pal[g][s] = ul.f;
            }
        }

        // ---- O += P·V, both groups (V frags shared) ----
#pragma unroll
        for (int c2 = 0; c2 < 4; ++c2) {
            const int row = 16 * c2 + fr;
            uint32_t r[8];
            bf16x8 vh0, vl0, vh1, vl1;
            *(u32x4*)&r[0] = *(u32x4*)&Vls[row][fq8];
            *(u32x4*)&r[4] = *(u32x4*)&Vls[row][fq8 + 4];
            unpk8(r, vh0, vl0);
            *(u32x4*)&r[0] = *(u32x4*)&Vls[row][32 + fq8];
            *(u32x4*)&r[4] = *(u32x4*)&Vls[row][32 + fq8 + 4];
            unpk8(r, vh1, vl1);
#pragma unroll
            for (int g = 0; g < 2; ++g) {
                f32x4 o = oA[g][c2];
                o = __builtin_amdgcn_mfma_f32_16x16x32_bf16(pah[g][0], vh0, o, 0, 0, 0);
                o = __builtin_amdgcn_mfma_f32_16x16x32_bf16(pah[g][1], vh1, o, 0, 0, 0);
                o = __builtin_amdgcn_mfma_f32_16x16x32_bf16(pah[g][0], vl0, o, 0, 0, 0);
                o = __builtin_amdgcn_mfma_f32_16x16x32_bf16(pah[g][1], vl1, o, 0, 0, 0);
                o = __builtin_amdgcn_mfma_f32_16x16x32_bf16(pal[g][0], vh0, o, 0, 0, 0);
                o = __builtin_amdgcn_mfma_f32_16x16x32_bf16(pal[g][1], vh1, o, 0, 0, 0);
                oA[g][c2] = o;
            }
        }

        __syncthreads();                 // all reads of this tile done
        if (t + 1 < NT) {                // write prefetched tile
#pragma unroll
            for (int i = 0; i < 4; ++i) {
                *(u32x4*)&Kls[sr][sc + i * 4] = kR[i];
                *(u32x4*)&Vls[sr][sc + i * 4] = vR[i];
            }
        }
    }

    // ---- epilogue ----
#pragma unroll
    for (int g = 0; g < 2; ++g) {
#pragma unroll
        for (int rr = 0; rr < 4; ++rr) {
            float lO = __shfl(lsum[g], 4 * fq + rr);
            int row = q0 + 16 * g + 4 * fq + rr;
            if (row < L_) {
                float inv = 1.f / lO;
#pragma unroll
                for (int c2 = 0; c2 < 4; ++c2)
                    O[obase + (size_t)row * D_ + 16 * c2 + fr] = oA[g][c2][rr] * inv;
            }
        }
    }
}

// ---------------- fused residual add + LayerNorm ----------------
__global__ __launch_bounds__(256) void add_ln_kernel(
    const float* __restrict__ X, const float* __restrict__ Y,
    const float* __restrict__ g, const float* __restrict__ be,
    float* __restrict__ Out) {
    int wave = threadIdx.x >> 6;
    int lane = threadIdx.x & 63;
    int row = blockIdx.x * 4 + wave;
    if (row >= M_) return;
    size_t base = (size_t)row * D_;
    int c0 = lane * 4, c1 = 256 + lane * 4;
    float4 xa = *(const float4*)&X[base + c0];
    float4 xb = *(const float4*)&X[base + c1];
    float4 ya = *(const float4*)&Y[base + c0];
    float4 yb = *(const float4*)&Y[base + c1];
    float v[8] = {xa.x + ya.x, xa.y + ya.y, xa.z + ya.z, xa.w + ya.w,
                  xb.x + yb.x, xb.y + yb.y, xb.z + yb.z, xb.w + yb.w};
    float s = 0.f, s2 = 0.f;
#pragma unroll
    for (int i = 0; i < 8; ++i) { s += v[i]; s2 = fmaf(v[i], v[i], s2); }
#pragma unroll
    for (int off = 32; off > 0; off >>= 1) {
        s  += __shfl_xor(s, off);
        s2 += __shfl_xor(s2, off);
    }
    float mean = s * (1.f / D_);
    float var  = s2 * (1.f / D_) - mean * mean;
    float rstd = rsqrtf(var + EPS_);
    float4 ga = *(const float4*)&g[c0];
    float4 gb = *(const float4*)&g[c1];
    float4 ba = *(const float4*)&be[c0];
    float4 bb = *(const float4*)&be[c1];
    float4 oa, ob;
    oa.x = (v[0] - mean) * rstd * ga.x + ba.x;
    oa.y = (v[1] - mean) * rstd * ga.y + ba.y;
    oa.z = (v[2] - mean) * rstd * ga.z + ba.z;
    oa.w = (v[3] - mean) * rstd * ga.w + ba.w;
    ob.x = (v[4] - mean) * rstd * gb.x + bb.x;
    ob.y = (v[5] - mean) * rstd * gb.y + bb.y;
    ob.z = (v[6] - mean) * rstd * gb.z + bb.z;
    ob.w = (v[7] - mean) * rstd * gb.w + bb.w;
    *(float4*)&Out[base + c0] = oa;
    *(float4*)&Out[base + c1] = ob;
}

// ---------------- launch ----------------
extern "C" void kernel_launch(void* const* d_in, const int* in_sizes, int n_in,
                              void* d_out, int out_size, void* d_ws, size_t ws_size,
                              hipStream_t stream) {
    const float* embed1 = (const float*)d_in[0];
    const float* embed2 = (const float*)d_in[1];
    const float* cls    = (const float*)d_in[2];
    const float* Wq = (const float*)d_in[3];
    const float* bq = (const float*)d_in[4];
    const float* Wk = (const float*)d_in[5];
    const float* bk = (const float*)d_in[6];
    const float* Wv = (const float*)d_in[7];
    const float* bv = (const float*)d_in[8];
    const float* Wo = (const float*)d_in[9];
    const float* bo = (const float*)d_in[10];
    const float* ln1g = (const float*)d_in[11];
    const float* ln1b = (const float*)d_in[12];
    const float* W1 = (const float*)d_in[13];
    const float* b1 = (const float*)d_in[14];
    const float* W2 = (const float*)d_in[15];
    const float* b2 = (const float*)d_in[16];
    const float* ln2g = (const float*)d_in[17];
    const float* ln2b = (const float*)d_in[18];

    const size_t SZ = (size_t)M_ * D_;        // 4,198,400
    float* ws = (float*)d_ws;
    float* X  = ws;                            // [0,SZ)
    float* X2 = ws + SZ;                       // [SZ,2SZ)
    float* Tb = ws + 2 * SZ;                   // [2SZ,3SZ)
    uint32_t* Qpk = (uint32_t*)(ws + 3 * SZ);  // packed hi|lo
    uint32_t* Kpk = (uint32_t*)(ws + 4 * SZ);
    uint32_t* Vpk = (uint32_t*)(ws + 5 * SZ);
    float* Hb = ws + 6 * SZ;                   // [6SZ,10SZ) fp32 [M,DFF] (FFN phase)
    uint32_t* Vtpk = (uint32_t*)(ws + 6 * SZ); // aliases Hb (attn phase)
    float* WoOut = (float*)Qpk;                // aliases Qpk (dead after attn)
    __bf16* wreg = (__bf16*)(ws + 10 * SZ);    // weight hi/lo planes

    const size_t NQ = (size_t)NLAYER_ * D_ * D_;       // 524288
    const size_t NF = (size_t)NLAYER_ * DFF_ * D_;     // 2097152
    __bf16* Wqh = wreg;            __bf16* Wql = Wqh + NQ;
    __bf16* Wkh = Wql + NQ;        __bf16* Wkl = Wkh + NQ;
    __bf16* Wvh = Wkl + NQ;        __bf16* Wvl = Wvh + NQ;
    __bf16* Woh = Wvl + NQ;        __bf16* Wol = Woh + NQ;
    __bf16* W1h = Wol + NQ;        __bf16* W1l = W1h + NF;
    __bf16* W2h = W1l + NF;        __bf16* W2l = W2h + NF;

    split_w_kernel<<<(int)(NQ / 4 + 255) / 256, 256, 0, stream>>>(Wq, Wqh, Wql, (int)(NQ / 4));
    split_w_kernel<<<(int)(NQ / 4 + 255) / 256, 256, 0, stream>>>(Wk, Wkh, Wkl, (int)(NQ / 4));
    split_w_kernel<<<(int)(NQ / 4 + 255) / 256, 256, 0, stream>>>(Wv, Wvh, Wvl, (int)(NQ / 4));
    split_w_kernel<<<(int)(NQ / 4 + 255) / 256, 256, 0, stream>>>(Wo, Woh, Wol, (int)(NQ / 4));
    split_w_kernel<<<(int)(NF / 4 + 255) / 256, 256, 0, stream>>>(W1, W1h, W1l, (int)(NF / 4));
    split_w_kernel<<<(int)(NF / 4 + 255) / 256, 256, 0, stream>>>(W2, W2h, W2l, (int)(NF / 4));

    write_cls_kernel<<<(B_ * D_) / 256, 256, 0, stream>>>(cls, X, X2);
    transpose_embed_kernel<<<dim3(L0_ / 32, D_ / 32, B_), dim3(32, 8), 0, stream>>>(embed1, X);
    transpose_embed_kernel<<<dim3(L0_ / 32, D_ / 32, B_), dim3(32, 8), 0, stream>>>(embed2, X2);

    const int GM = (M_ + 127) / 128;         // 65
    const int g512  = GM * (512 / 64);       // 520
    const int g2048 = GM * (2048 / 64);      // 2080

    for (int l = 0; l < NLAYER_; ++l) {
        const size_t oQ = (size_t)l * D_ * D_;
        const size_t oF = (size_t)l * DFF_ * D_;

        gemm_mfma_kernel<false, true><<<g512, 256, 0, stream>>>(
            X, Wqh + oQ, Wql + oQ, bq + l * D_, nullptr, Qpk, M_, D_, D_);
        gemm_mfma_kernel<false, true><<<g512, 256, 0, stream>>>(
            X2, Wkh + oQ, Wkl + oQ, bk + l * D_, nullptr, Kpk, M_, D_, D_);
        gemm_mfma_kernel<false, true><<<g512, 256, 0, stream>>>(
            X2, Wvh + oQ, Wvl + oQ, bv + l * D_, nullptr, Vpk, M_, D_, D_);

        transpose_v_kernel<<<dim3(LP_ / 32, DH_ / 32, B_ * H_), dim3(32, 8), 0, stream>>>(
            Vpk, Vtpk);

        attn_mfma_kernel<<<dim3((L_ + 127) / 128, H_, B_), 256, 0, stream>>>(
            Qpk, Kpk, Vtpk, Tb);

        gemm_mfma_kernel<false, false><<<g512, 256, 0, stream>>>(
            Tb, Woh + oQ, Wol + oQ, bo + l * D_, WoOut, nullptr, M_, D_, D_);

        add_ln_kernel<<<(M_ + 3) / 4, 256, 0, stream>>>(
            X, WoOut, ln1g + l * D_, ln1b + l * D_, X);

        gemm_mfma_kernel<true, false><<<g2048, 256, 0, stream>>>(
            X, W1h + oF, W1l + oF, b1 + l * DFF_, Hb, nullptr, M_, DFF_, D_);
        gemm_mfma_kernel<false, false><<<g512, 256, 0, stream>>>(
            Hb, W2h + oF, W2l + oF, b2 + l * D_, Tb, nullptr, M_, D_, DFF_);

        float* out_ptr = (l == NLAYER_ - 1) ? (float*)d_out : X;
        add_ln_kernel<<<(M_ + 3) / 4, 256, 0, stream>>>(
            X, Tb, ln2g + l * D_, ln2b + l * D_, out_ptr);
    }
}